// Round 1
// baseline (158.413 us; speedup 1.0000x reference)
//
#include <hip/hip_runtime.h>
#include <hip/hip_bf16.h>
#include <math.h>

// B=2, C=128, H=W=64, heads=4, head_dim=32, kernel=7 (49 taps), depth=2.
// Inputs fp32, OUTPUT fp32. Intermediates bf16. MFMA GEMMs.
// R19: chain-shortening pass (8 -> 6 dispatches), numerics-identical:
//   - cvtw deleted: all GEMMs read fp32 weights, convert to bf16 in-register
//     (same RNE rounding as cvtw -> identical weight values).
//   - proj1 + LayerNorm + NCHW transpose fused into projln (LN on fp32 acc,
//     removes 2MB+2MB y round-trip and one launch).
//   - attn scratch moved to workspace (projln output would alias it in d_out).
// Chain: xqkv | attn0 | proj0 | qkv1 | attn1 | projln.
#define PIX 8192
typedef __hip_bfloat16 bf16;
typedef __attribute__((ext_vector_type(8))) short short8;
typedef __attribute__((ext_vector_type(4))) float f32x4;

__device__ inline float bflo(unsigned u) { return __uint_as_float(u << 16); }
__device__ inline float bfhi(unsigned u) { return __uint_as_float(u & 0xffff0000u); }
__device__ inline unsigned short f2b(float f) {
  __hip_bfloat16 h = __float2bfloat16(f);
  return *reinterpret_cast<unsigned short*>(&h);
}
__device__ inline unsigned pack2(float a, float b) {
  return (unsigned)f2b(a) | ((unsigned)f2b(b) << 16);
}
// load 8 consecutive fp32 weights, convert to a bf16 MFMA fragment
__device__ inline short8 ldw8(const float* __restrict__ p) {
  f32x4 lo = *(const f32x4*)p;
  f32x4 hi = *(const f32x4*)(p + 4);
  short8 r;
  r[0] = (short)f2b(lo[0]); r[1] = (short)f2b(lo[1]);
  r[2] = (short)f2b(lo[2]); r[3] = (short)f2b(lo[3]);
  r[4] = (short)f2b(hi[0]); r[5] = (short)f2b(hi[1]);
  r[6] = (short)f2b(hi[2]); r[7] = (short)f2b(hi[3]);
  return r;
}

// ---------- fused transpose + qkv0: x (NCHW fp32) -> qkv (bf16) ----------
// 512 blocks x 16 px. Stage 16x128 bf16 A-tile in LDS (stride 136), then
// wave w -> cols [96w, 96w+96), A-frag row = lane&15. Weights read fp32
// directly (L2-resident), converted in-register.
__global__ __launch_bounds__(256) void xqkv(const float* __restrict__ x,
                                            const float* __restrict__ qw,
                                            const float* __restrict__ qb,
                                            unsigned short* __restrict__ qkv) {
  __shared__ __align__(16) unsigned short As[16 * 136];
  int m0 = blockIdx.x * 16;
  int tid = threadIdx.x;
  int b = m0 >> 12, i = (m0 >> 6) & 63, j0 = m0 & 63;

  for (int idx = tid; idx < 2048; idx += 256) {
    int c = idx >> 4, jl = idx & 15;
    As[jl * 136 + c] =
        f2b(x[(size_t)b * 524288 + (size_t)c * 4096 + i * 64 + j0 + jl]);
  }
  __syncthreads();

  int w = tid >> 6, lane = tid & 63;
  int quad = lane >> 4, l16 = lane & 15;
  short8 a[4];
#pragma unroll
  for (int kc = 0; kc < 4; ++kc)
    a[kc] = *(const short8*)(As + l16 * 136 + kc * 32 + quad * 8);
#pragma unroll
  for (int nt = 0; nt < 6; ++nt) {
    int col = w * 96 + nt * 16 + l16;
    const float* wrow = qw + (size_t)col * 128 + quad * 8;
    f32x4 c = {0.f, 0.f, 0.f, 0.f};
#pragma unroll
    for (int kc = 0; kc < 4; ++kc)
      c = __builtin_amdgcn_mfma_f32_16x16x32_bf16(a[kc], ldw8(wrow + kc * 32), c, 0, 0, 0);
    float bv = qb[col];
#pragma unroll
    for (int r2 = 0; r2 < 4; ++r2)
      qkv[(size_t)(m0 + quad * 4 + r2) * 384 + col] = f2b(c[r2] + bv);
  }
}

// ---------- MFMA GEMM: C[M,N] = A[M,128] * W[N,128]^T + bias ----------
// W is fp32 (converted to bf16 in-register, identical rounding to old cvtw).
__global__ __launch_bounds__(256) void gemm_mfma(const unsigned short* __restrict__ A,
                                                 const float* __restrict__ Wf,
                                                 const float* __restrict__ bias,
                                                 unsigned short* __restrict__ Cmat,
                                                 int N) {
  int m0 = blockIdx.x * 64, n0 = blockIdx.y * 64;
  int tid = threadIdx.x;
  int w = tid >> 6, lane = tid & 63;
  int quad = lane >> 4, l16 = lane & 15;

  const short8* ap =
      (const short8*)(A + (size_t)(m0 + w * 16 + l16) * 128 + quad * 8);
  short8 a[4];
#pragma unroll
  for (int kc = 0; kc < 4; ++kc) a[kc] = ap[kc * 4];

  f32x4 acc[4];
#pragma unroll
  for (int nt = 0; nt < 4; ++nt) {
    const float* wrow = Wf + (size_t)(n0 + nt * 16 + l16) * 128 + quad * 8;
    f32x4 c = {0.f, 0.f, 0.f, 0.f};
#pragma unroll
    for (int kc = 0; kc < 4; ++kc)
      c = __builtin_amdgcn_mfma_f32_16x16x32_bf16(a[kc], ldw8(wrow + kc * 32), c, 0, 0, 0);
    acc[nt] = c;
  }

#pragma unroll
  for (int nt = 0; nt < 4; ++nt) {
    int col = n0 + nt * 16 + l16;
    float bv = bias[col];
#pragma unroll
    for (int r = 0; r < 4; ++r) {
      int m = m0 + w * 16 + quad * 4 + r;
      Cmat[(size_t)m * N + col] = f2b(acc[nt][r] + bv);
    }
  }
}

// ---------- neighborhood attention v6 (unchanged) ----------
#define RSTRIDE 72
__global__ __launch_bounds__(256, 2) void na_attn(const unsigned short* __restrict__ qkvp,
                                                  const float* __restrict__ rpb,
                                                  unsigned short* __restrict__ out) {
  __shared__ __align__(16) unsigned short kbuf[140 * RSTRIDE];
  __shared__ __align__(16) unsigned short vbuf[140 * RSTRIDE];
  __shared__ float rb[338];
  __shared__ float sc[64][52];

  int ti = blockIdx.x >> 4, tj = blockIdx.x & 15;   // 8 x 16 tiles of 8x4 px
  int hp = blockIdx.y;
  int bz = blockIdx.z;
  int tid = threadIdx.x;
  int bi0 = ti * 8 - 3, bj0 = tj * 4 - 3;           // halo origin

  for (int t = tid; t < 338; t += 256) rb[t] = rpb[hp * 338 + t];

  for (int t = tid; t < 2240; t += 256) {
    int row = t >> 4;            // 0..139
    int sub = t & 15;
    int isv = sub >> 3;          // 0=K, 1=V
    int c = sub & 7;
    int ri = row / 10, rj = row - ri * 10;
    int gi = bi0 + ri, gj = bj0 + rj;
    uint4 val = make_uint4(0, 0, 0, 0);
    if ((unsigned)gi < 64u && (unsigned)gj < 64u) {
      int pixn = (bz * 64 + gi) * 64 + gj;
      val = *(const uint4*)(qkvp + (size_t)pixn * 384 + 128 + isv * 128 +
                            hp * 64 + c * 8);
    }
    *(uint4*)((isv ? vbuf : kbuf) + row * RSTRIDE + c * 8) = val;
  }
  __syncthreads();

  int r = tid & 3;
  int hl = (tid >> 2) & 1;
  int px = tid >> 3;
  int ph = px * 2 + hl;
  int pi = px >> 2, pj = px & 3;
  int i = ti * 8 + pi, j = tj * 4 + pj;
  int si = min(max(i - 3, 0), 57), sj = min(max(j - 3, 0), 57);
  int li = si - bi0, lj = sj - bj0;
  int oi = i - si, oj = j - sj;
  int H = hp * 2 + hl;
  int pix = (bz * 64 + i) * 64 + j;

  const float scale = 0.17677669529663687f;   // 32^-0.5
  float q[8];
  {
    uint4 t = *(const uint4*)(qkvp + (size_t)pix * 384 + H * 32 + r * 8);
    q[0] = bflo(t.x) * scale;  q[1] = bfhi(t.x) * scale;
    q[2] = bflo(t.y) * scale;  q[3] = bfhi(t.y) * scale;
    q[4] = bflo(t.z) * scale;  q[5] = bfhi(t.z) * scale;
    q[6] = bflo(t.w) * scale;  q[7] = bfhi(t.w) * scale;
  }

  const unsigned short* kh = kbuf + hl * 32 + r * 8;
  const unsigned short* vh = vbuf + hl * 32 + r * 8;
  const float* rbh = rb + hl * 169;

#pragma unroll
  for (int p = 0; p < 7; ++p) {
#pragma unroll
    for (int qq = 0; qq < 7; ++qq) {
      int n = (li + p) * 10 + (lj + qq);
      uint4 t = *(const uint4*)(kh + n * RSTRIDE);
      float dot = q[0] * bflo(t.x) + q[1] * bfhi(t.x)
                + q[2] * bflo(t.y) + q[3] * bfhi(t.y)
                + q[4] * bflo(t.z) + q[5] * bfhi(t.z)
                + q[6] * bflo(t.w) + q[7] * bfhi(t.w);
      dot += __shfl_xor(dot, 1);
      dot += __shfl_xor(dot, 2);
      if (r == 0) sc[ph][p * 7 + qq] = dot + rbh[(p + 6 - oi) * 13 + (qq + 6 - oj)];
    }
  }
  __syncthreads();

  float m = -INFINITY;
#pragma unroll
  for (int n = 0; n < 49; ++n) m = fmaxf(m, sc[ph][n]);

  float sum = 0.f;
  float acc[8] = {0.f, 0.f, 0.f, 0.f, 0.f, 0.f, 0.f, 0.f};
#pragma unroll
  for (int p = 0; p < 7; ++p) {
#pragma unroll
    for (int qq = 0; qq < 7; ++qq) {
      float e = __expf(sc[ph][p * 7 + qq] - m);
      sum += e;
      int n = (li + p) * 10 + (lj + qq);
      uint4 t = *(const uint4*)(vh + n * RSTRIDE);
      acc[0] += e * bflo(t.x);  acc[1] += e * bfhi(t.x);
      acc[2] += e * bflo(t.y);  acc[3] += e * bfhi(t.y);
      acc[4] += e * bflo(t.z);  acc[5] += e * bfhi(t.z);
      acc[6] += e * bflo(t.w);  acc[7] += e * bfhi(t.w);
    }
  }
  float inv = 1.f / sum;
  uint4 t;
  t.x = pack2(acc[0] * inv, acc[1] * inv);
  t.y = pack2(acc[2] * inv, acc[3] * inv);
  t.z = pack2(acc[4] * inv, acc[5] * inv);
  t.w = pack2(acc[6] * inv, acc[7] * inv);
  *(uint4*)(out + (size_t)pix * 128 + H * 32 + r * 8) = t;
}

// ---------- fused proj1 + LayerNorm + transpose to (B,C,H,W) fp32 ----------
// One block per (b,i) row of 64 pixels. MFMA proj (full 128 cols), fp32 acc
// into LDS tile, LN over C on fp32, coalesced transposed store.
__global__ __launch_bounds__(256) void projln(const unsigned short* __restrict__ A,
                                              const float* __restrict__ Wf,
                                              const float* __restrict__ bias,
                                              const float* __restrict__ g,
                                              const float* __restrict__ bta,
                                              float* __restrict__ out) {
  __shared__ float tile[64][129];
  __shared__ float mean_s[64], rstd_s[64];
  int blk = blockIdx.x;                     // b*64 + i
  int b = blk >> 6, i = blk & 63;
  int m0 = blk * 64;
  int tid = threadIdx.x;
  int w = tid >> 6, lane = tid & 63;
  int quad = lane >> 4, l16 = lane & 15;

  const short8* ap =
      (const short8*)(A + (size_t)(m0 + w * 16 + l16) * 128 + quad * 8);
  short8 a[4];
#pragma unroll
  for (int kc = 0; kc < 4; ++kc) a[kc] = ap[kc * 4];

#pragma unroll
  for (int nt = 0; nt < 8; ++nt) {
    int col = nt * 16 + l16;
    const float* wrow = Wf + (size_t)col * 128 + quad * 8;
    f32x4 c = {0.f, 0.f, 0.f, 0.f};
#pragma unroll
    for (int kc = 0; kc < 4; ++kc)
      c = __builtin_amdgcn_mfma_f32_16x16x32_bf16(a[kc], ldw8(wrow + kc * 32), c, 0, 0, 0);
    float bv = bias[col];
#pragma unroll
    for (int r = 0; r < 4; ++r)
      tile[w * 16 + quad * 4 + r][col] = c[r] + bv;
  }
  __syncthreads();

  int jj = tid >> 2, qtr = tid & 3;
  float sum = 0.f, sumsq = 0.f;
#pragma unroll
  for (int cc = 0; cc < 32; ++cc) {
    float v = tile[jj][qtr * 32 + cc];
    sum += v; sumsq += v * v;
  }
  sum += __shfl_xor(sum, 1);  sum += __shfl_xor(sum, 2);
  sumsq += __shfl_xor(sumsq, 1);  sumsq += __shfl_xor(sumsq, 2);
  if (qtr == 0) {
    float mu = sum * (1.f / 128.f);
    mean_s[jj] = mu;
    rstd_s[jj] = rsqrtf(sumsq * (1.f / 128.f) - mu * mu + 1e-5f);
  }
  __syncthreads();
  int c0 = tid >> 6;
  int j = tid & 63;
  for (int c = c0; c < 128; c += 4) {
    float v = (tile[j][c] - mean_s[j]) * rstd_s[j] * g[c] + bta[c];
    out[(((size_t)b * 128 + c) * 64 + i) * 64 + j] = v;
  }
}

extern "C" void kernel_launch(void* const* d_in, const int* in_sizes, int n_in,
                              void* d_out, int out_size, void* d_ws, size_t ws_size,
                              hipStream_t stream) {
  (void)in_sizes; (void)n_in; (void)out_size; (void)ws_size;
  const float* x   = (const float*)d_in[0];
  const float* qw  = (const float*)d_in[1];   // (2,384,128)
  const float* qb  = (const float*)d_in[2];   // (2,384)
  const float* rpb = (const float*)d_in[3];   // (2,4,13,13)
  const float* pw  = (const float*)d_in[4];   // (2,128,128)
  const float* pb  = (const float*)d_in[5];   // (2,128)
  const float* lg  = (const float*)d_in[6];
  const float* lb  = (const float*)d_in[7];

  unsigned short* y    = (unsigned short*)d_ws;          // proj0 output (2 MB)
  unsigned short* qkv  = y + (size_t)PIX * 128;          // PIX*384 (6 MB)
  unsigned short* attn = qkv + (size_t)PIX * 384;        // PIX*128 (2 MB)
  float* out = (float*)d_out;

  xqkv<<<512, 256, 0, stream>>>(x, qw, qb, qkv);                            // qkv0
  na_attn<<<dim3(128, 2, 2), 256, 0, stream>>>(qkv, rpb, attn);             // attn0
  gemm_mfma<<<dim3(128, 2), 256, 0, stream>>>(attn, pw, pb, y, 128);        // proj0
  gemm_mfma<<<dim3(128, 6), 256, 0, stream>>>(y, qw + 49152, qb + 384, qkv, 384); // qkv1
  na_attn<<<dim3(128, 2, 2), 256, 0, stream>>>(qkv, rpb + 676, attn);       // attn1
  projln<<<128, 256, 0, stream>>>(attn, pw + 16384, pb + 128, lg, lb, out); // proj1+LN
}

// Round 2
// 147.766 us; speedup vs baseline: 1.0721x; 1.0721x over previous
//
#include <hip/hip_runtime.h>
#include <hip/hip_bf16.h>
#include <math.h>

// B=2, C=128, H=W=64, heads=4, head_dim=32, kernel=7 (49 taps), depth=2.
// Inputs fp32, OUTPUT fp32. Intermediates bf16. MFMA GEMMs.
// R20: revert R19 (regressed 146->158: fp32-weight in-register cvt on GEMM
// critical paths + projln parallelism halving). Back to R18 structure with
// ONE delta: cvtw folded into kernel-1 as 128 tail blocks (grid 640) that
// convert downstream weights (qkv-L1 + proj both layers); the 512 xqkv
// blocks convert their own L0 weights in-register (bounded, off the
// downstream GEMMs). Downstream GEMMs read pre-converted bf16 (as R18).
// Chain (7): xqkv_cvt | attn0 | proj0 | qkv1 | attn1 | proj1 | ln_out.
#define PIX 8192
typedef __hip_bfloat16 bf16;
typedef __attribute__((ext_vector_type(8))) short short8;
typedef __attribute__((ext_vector_type(4))) float f32x4;

__device__ inline float bflo(unsigned u) { return __uint_as_float(u << 16); }
__device__ inline float bfhi(unsigned u) { return __uint_as_float(u & 0xffff0000u); }
__device__ inline unsigned short f2b(float f) {
  __hip_bfloat16 h = __float2bfloat16(f);
  return *reinterpret_cast<unsigned short*>(&h);
}
__device__ inline unsigned pack2(float a, float b) {
  return (unsigned)f2b(a) | ((unsigned)f2b(b) << 16);
}
// load 8 consecutive fp32 weights, convert to a bf16 MFMA fragment (xqkv only)
__device__ inline short8 ldw8(const float* __restrict__ p) {
  f32x4 lo = *(const f32x4*)p;
  f32x4 hi = *(const f32x4*)(p + 4);
  short8 r;
  r[0] = (short)f2b(lo[0]); r[1] = (short)f2b(lo[1]);
  r[2] = (short)f2b(lo[2]); r[3] = (short)f2b(lo[3]);
  r[4] = (short)f2b(hi[0]); r[5] = (short)f2b(hi[1]);
  r[6] = (short)f2b(hi[2]); r[7] = (short)f2b(hi[3]);
  return r;
}

// ---------- kernel 1: fused transpose+qkv0 (blocks 0..511) + weight cvt ----
// xqkv part: 512 blocks x 16 px. Stage 16x128 bf16 A-tile in LDS (stride
// 136); wave w -> cols [96w, 96w+96), A-frag row = lane&15. L0 qkv weights
// read fp32, converted in-register. Tail 128 blocks: convert L1 qkv weights
// (49152) + both proj weight layers (32768) to bf16 for downstream GEMMs.
__global__ __launch_bounds__(256) void xqkv_cvt(const float* __restrict__ x,
                                                const float* __restrict__ qw,
                                                const float* __restrict__ qb,
                                                unsigned short* __restrict__ qkv,
                                                const float* __restrict__ pw,
                                                unsigned short* __restrict__ wq1,
                                                unsigned short* __restrict__ wp) {
  if (blockIdx.x >= 512) {                     // weight-conversion tail blocks
    int idx = (blockIdx.x - 512) * 256 + threadIdx.x;   // 0..32767
    wq1[idx] = f2b(qw[49152 + idx]);
    wq1[idx + 16384] = f2b(qw[49152 + idx + 16384]);
    if (idx < 16384) wq1[idx + 32768] = f2b(qw[49152 + idx + 32768]);
    wp[idx] = f2b(pw[idx]);
    return;
  }

  __shared__ __align__(16) unsigned short As[16 * 136];
  int m0 = blockIdx.x * 16;
  int tid = threadIdx.x;
  int b = m0 >> 12, i = (m0 >> 6) & 63, j0 = m0 & 63;

  for (int idx = tid; idx < 2048; idx += 256) {
    int c = idx >> 4, jl = idx & 15;
    As[jl * 136 + c] =
        f2b(x[(size_t)b * 524288 + (size_t)c * 4096 + i * 64 + j0 + jl]);
  }
  __syncthreads();

  int w = tid >> 6, lane = tid & 63;
  int quad = lane >> 4, l16 = lane & 15;
  short8 a[4];
#pragma unroll
  for (int kc = 0; kc < 4; ++kc)
    a[kc] = *(const short8*)(As + l16 * 136 + kc * 32 + quad * 8);
#pragma unroll
  for (int nt = 0; nt < 6; ++nt) {
    int col = w * 96 + nt * 16 + l16;
    const float* wrow = qw + (size_t)col * 128 + quad * 8;
    f32x4 c = {0.f, 0.f, 0.f, 0.f};
#pragma unroll
    for (int kc = 0; kc < 4; ++kc)
      c = __builtin_amdgcn_mfma_f32_16x16x32_bf16(a[kc], ldw8(wrow + kc * 32), c, 0, 0, 0);
    float bv = qb[col];
#pragma unroll
    for (int r2 = 0; r2 < 4; ++r2)
      qkv[(size_t)(m0 + quad * 4 + r2) * 384 + col] = f2b(c[r2] + bv);
  }
}

// ---------- MFMA GEMM: C[M,N] = A[M,128] * W[N,128]^T + bias (bf16 W) ------
__global__ __launch_bounds__(256) void gemm_mfma(const unsigned short* __restrict__ A,
                                                 const unsigned short* __restrict__ W,
                                                 const float* __restrict__ bias,
                                                 unsigned short* __restrict__ Cmat,
                                                 int N) {
  int m0 = blockIdx.x * 64, n0 = blockIdx.y * 64;
  int tid = threadIdx.x;
  int w = tid >> 6, lane = tid & 63;
  int quad = lane >> 4, l16 = lane & 15;

  const short8* ap =
      (const short8*)(A + (size_t)(m0 + w * 16 + l16) * 128 + quad * 8);
  short8 a[4];
#pragma unroll
  for (int kc = 0; kc < 4; ++kc) a[kc] = ap[kc * 4];

  f32x4 acc[4];
#pragma unroll
  for (int nt = 0; nt < 4; ++nt) {
    const short8* bp =
        (const short8*)(W + (size_t)(n0 + nt * 16 + l16) * 128 + quad * 8);
    f32x4 c = {0.f, 0.f, 0.f, 0.f};
#pragma unroll
    for (int kc = 0; kc < 4; ++kc)
      c = __builtin_amdgcn_mfma_f32_16x16x32_bf16(a[kc], bp[kc * 4], c, 0, 0, 0);
    acc[nt] = c;
  }

#pragma unroll
  for (int nt = 0; nt < 4; ++nt) {
    int col = n0 + nt * 16 + l16;
    float bv = bias[col];
#pragma unroll
    for (int r = 0; r < 4; ++r) {
      int m = m0 + w * 16 + quad * 4 + r;
      Cmat[(size_t)m * N + col] = f2b(acc[nt][r] + bv);
    }
  }
}

// ---------- neighborhood attention v6 (unchanged) ----------
#define RSTRIDE 72
__global__ __launch_bounds__(256, 2) void na_attn(const unsigned short* __restrict__ qkvp,
                                                  const float* __restrict__ rpb,
                                                  unsigned short* __restrict__ out) {
  __shared__ __align__(16) unsigned short kbuf[140 * RSTRIDE];
  __shared__ __align__(16) unsigned short vbuf[140 * RSTRIDE];
  __shared__ float rb[338];
  __shared__ float sc[64][52];

  int ti = blockIdx.x >> 4, tj = blockIdx.x & 15;   // 8 x 16 tiles of 8x4 px
  int hp = blockIdx.y;
  int bz = blockIdx.z;
  int tid = threadIdx.x;
  int bi0 = ti * 8 - 3, bj0 = tj * 4 - 3;           // halo origin

  for (int t = tid; t < 338; t += 256) rb[t] = rpb[hp * 338 + t];

  for (int t = tid; t < 2240; t += 256) {
    int row = t >> 4;            // 0..139
    int sub = t & 15;
    int isv = sub >> 3;          // 0=K, 1=V
    int c = sub & 7;
    int ri = row / 10, rj = row - ri * 10;
    int gi = bi0 + ri, gj = bj0 + rj;
    uint4 val = make_uint4(0, 0, 0, 0);
    if ((unsigned)gi < 64u && (unsigned)gj < 64u) {
      int pixn = (bz * 64 + gi) * 64 + gj;
      val = *(const uint4*)(qkvp + (size_t)pixn * 384 + 128 + isv * 128 +
                            hp * 64 + c * 8);
    }
    *(uint4*)((isv ? vbuf : kbuf) + row * RSTRIDE + c * 8) = val;
  }
  __syncthreads();

  int r = tid & 3;
  int hl = (tid >> 2) & 1;
  int px = tid >> 3;
  int ph = px * 2 + hl;
  int pi = px >> 2, pj = px & 3;
  int i = ti * 8 + pi, j = tj * 4 + pj;
  int si = min(max(i - 3, 0), 57), sj = min(max(j - 3, 0), 57);
  int li = si - bi0, lj = sj - bj0;
  int oi = i - si, oj = j - sj;
  int H = hp * 2 + hl;
  int pix = (bz * 64 + i) * 64 + j;

  const float scale = 0.17677669529663687f;   // 32^-0.5
  float q[8];
  {
    uint4 t = *(const uint4*)(qkvp + (size_t)pix * 384 + H * 32 + r * 8);
    q[0] = bflo(t.x) * scale;  q[1] = bfhi(t.x) * scale;
    q[2] = bflo(t.y) * scale;  q[3] = bfhi(t.y) * scale;
    q[4] = bflo(t.z) * scale;  q[5] = bfhi(t.z) * scale;
    q[6] = bflo(t.w) * scale;  q[7] = bfhi(t.w) * scale;
  }

  const unsigned short* kh = kbuf + hl * 32 + r * 8;
  const unsigned short* vh = vbuf + hl * 32 + r * 8;
  const float* rbh = rb + hl * 169;

#pragma unroll
  for (int p = 0; p < 7; ++p) {
#pragma unroll
    for (int qq = 0; qq < 7; ++qq) {
      int n = (li + p) * 10 + (lj + qq);
      uint4 t = *(const uint4*)(kh + n * RSTRIDE);
      float dot = q[0] * bflo(t.x) + q[1] * bfhi(t.x)
                + q[2] * bflo(t.y) + q[3] * bfhi(t.y)
                + q[4] * bflo(t.z) + q[5] * bfhi(t.z)
                + q[6] * bflo(t.w) + q[7] * bfhi(t.w);
      dot += __shfl_xor(dot, 1);
      dot += __shfl_xor(dot, 2);
      if (r == 0) sc[ph][p * 7 + qq] = dot + rbh[(p + 6 - oi) * 13 + (qq + 6 - oj)];
    }
  }
  __syncthreads();

  float m = -INFINITY;
#pragma unroll
  for (int n = 0; n < 49; ++n) m = fmaxf(m, sc[ph][n]);

  float sum = 0.f;
  float acc[8] = {0.f, 0.f, 0.f, 0.f, 0.f, 0.f, 0.f, 0.f};
#pragma unroll
  for (int p = 0; p < 7; ++p) {
#pragma unroll
    for (int qq = 0; qq < 7; ++qq) {
      float e = __expf(sc[ph][p * 7 + qq] - m);
      sum += e;
      int n = (li + p) * 10 + (lj + qq);
      uint4 t = *(const uint4*)(vh + n * RSTRIDE);
      acc[0] += e * bflo(t.x);  acc[1] += e * bfhi(t.x);
      acc[2] += e * bflo(t.y);  acc[3] += e * bfhi(t.y);
      acc[4] += e * bflo(t.z);  acc[5] += e * bfhi(t.z);
      acc[6] += e * bflo(t.w);  acc[7] += e * bfhi(t.w);
    }
  }
  float inv = 1.f / sum;
  uint4 t;
  t.x = pack2(acc[0] * inv, acc[1] * inv);
  t.y = pack2(acc[2] * inv, acc[3] * inv);
  t.z = pack2(acc[4] * inv, acc[5] * inv);
  t.w = pack2(acc[6] * inv, acc[7] * inv);
  *(uint4*)(out + (size_t)pix * 128 + H * 32 + r * 8) = t;
}

// ---------- LayerNorm over C + transpose to (B,C,H,W), fp32 store ----------
__global__ __launch_bounds__(256) void ln_out(const unsigned short* __restrict__ y,
                                              const float* __restrict__ g,
                                              const float* __restrict__ bta,
                                              float* __restrict__ out) {
  __shared__ float tile[64][129];
  __shared__ float mean_s[64], rstd_s[64];
  int blk = blockIdx.x;
  int b = blk >> 6, i = blk & 63;
  int tid = threadIdx.x;
  const unsigned short* yrow = y + (size_t)blk * 64 * 128;
  for (int idx = tid; idx < 8192; idx += 256) {
    int j = idx >> 7, c = idx & 127;
    tile[j][c] = __uint_as_float((unsigned)yrow[idx] << 16);
  }
  __syncthreads();
  int jj = tid >> 2, qtr = tid & 3;
  float sum = 0.f, sumsq = 0.f;
#pragma unroll
  for (int cc = 0; cc < 32; ++cc) {
    float v = tile[jj][qtr * 32 + cc];
    sum += v; sumsq += v * v;
  }
  sum += __shfl_xor(sum, 1);  sum += __shfl_xor(sum, 2);
  sumsq += __shfl_xor(sumsq, 1);  sumsq += __shfl_xor(sumsq, 2);
  if (qtr == 0) {
    float mu = sum * (1.f / 128.f);
    mean_s[jj] = mu;
    rstd_s[jj] = rsqrtf(sumsq * (1.f / 128.f) - mu * mu + 1e-5f);
  }
  __syncthreads();
  int c0 = tid >> 6;
  int j = tid & 63;
  for (int c = c0; c < 128; c += 4) {
    float v = (tile[j][c] - mean_s[j]) * rstd_s[j] * g[c] + bta[c];
    out[(((size_t)b * 128 + c) * 64 + i) * 64 + j] = v;
  }
}

extern "C" void kernel_launch(void* const* d_in, const int* in_sizes, int n_in,
                              void* d_out, int out_size, void* d_ws, size_t ws_size,
                              hipStream_t stream) {
  (void)in_sizes; (void)n_in; (void)out_size; (void)ws_size;
  const float* x   = (const float*)d_in[0];
  const float* qw  = (const float*)d_in[1];   // (2,384,128)
  const float* qb  = (const float*)d_in[2];   // (2,384)
  const float* rpb = (const float*)d_in[3];   // (2,4,13,13)
  const float* pw  = (const float*)d_in[4];   // (2,128,128)
  const float* pb  = (const float*)d_in[5];   // (2,128)
  const float* lg  = (const float*)d_in[6];
  const float* lb  = (const float*)d_in[7];

  unsigned short* y    = (unsigned short*)d_ws;          // proj outputs (2 MB)
  unsigned short* qkv  = y + (size_t)PIX * 128;          // PIX*384 (6 MB)
  unsigned short* wq1  = qkv + (size_t)PIX * 384;        // 49152 (L1 qkv w)
  unsigned short* wp   = wq1 + 49152;                    // 32768 (proj w, both)
  unsigned short* attn = (unsigned short*)d_out;         // PIX*128 (scratch)
  float* out = (float*)d_out;

  xqkv_cvt<<<640, 256, 0, stream>>>(x, qw, qb, qkv, pw, wq1, wp);          // qkv0+cvt
  na_attn<<<dim3(128, 2, 2), 256, 0, stream>>>(qkv, rpb, attn);            // attn0
  gemm_mfma<<<dim3(128, 2), 256, 0, stream>>>(attn, wp, pb, y, 128);       // proj0
  gemm_mfma<<<dim3(128, 6), 256, 0, stream>>>(y, wq1, qb + 384, qkv, 384); // qkv1
  na_attn<<<dim3(128, 2, 2), 256, 0, stream>>>(qkv, rpb + 676, attn);      // attn1
  gemm_mfma<<<dim3(128, 2), 256, 0, stream>>>(attn, wp + 16384, pb + 128, y, 128); // proj1
  ln_out<<<128, 256, 0, stream>>>(y, lg, lb, out);                         // LN
}

// Round 3
// 139.063 us; speedup vs baseline: 1.1392x; 1.0626x over previous
//
#include <hip/hip_runtime.h>
#include <hip/hip_bf16.h>
#include <math.h>

// B=2, C=128, H=W=64, heads=4, head_dim=32, kernel=7 (49 taps), depth=2.
// Inputs fp32, OUTPUT fp32. Intermediates bf16. MFMA GEMMs.
// R21: fuse proj into attn. attn blocks now cover ALL 4 heads (512 thr,
// grid 256 = 1 block/CU, 8 waves = same waves/CU as before), so each block
// holds full 128-ch rows for its 32 px -> proj via MFMA in-kernel, write y.
// Removes proj dispatches (2), attn-out global round-trip (2MB w + 2MB r
// per layer), d_out scratch. Proj numerics bit-identical to R20.
// ln_out: vectorized uint4 single-pass load+reduce (was 32 scalar u16/thr).
// Chain (5): xqkv_cvt | attnproj0 | qkv1 | attnproj1 | ln_out.
#define PIX 8192
typedef __hip_bfloat16 bf16;
typedef __attribute__((ext_vector_type(8))) short short8;
typedef __attribute__((ext_vector_type(4))) float f32x4;

__device__ inline float bflo(unsigned u) { return __uint_as_float(u << 16); }
__device__ inline float bfhi(unsigned u) { return __uint_as_float(u & 0xffff0000u); }
__device__ inline unsigned short f2b(float f) {
  __hip_bfloat16 h = __float2bfloat16(f);
  return *reinterpret_cast<unsigned short*>(&h);
}
__device__ inline unsigned pack2(float a, float b) {
  return (unsigned)f2b(a) | ((unsigned)f2b(b) << 16);
}
// load 8 consecutive fp32 weights, convert to a bf16 MFMA fragment (xqkv only)
__device__ inline short8 ldw8(const float* __restrict__ p) {
  f32x4 lo = *(const f32x4*)p;
  f32x4 hi = *(const f32x4*)(p + 4);
  short8 r;
  r[0] = (short)f2b(lo[0]); r[1] = (short)f2b(lo[1]);
  r[2] = (short)f2b(lo[2]); r[3] = (short)f2b(lo[3]);
  r[4] = (short)f2b(hi[0]); r[5] = (short)f2b(hi[1]);
  r[6] = (short)f2b(hi[2]); r[7] = (short)f2b(hi[3]);
  return r;
}

// ---------- kernel 1: fused transpose+qkv0 (blocks 0..511) + weight cvt ----
__global__ __launch_bounds__(256) void xqkv_cvt(const float* __restrict__ x,
                                                const float* __restrict__ qw,
                                                const float* __restrict__ qb,
                                                unsigned short* __restrict__ qkv,
                                                const float* __restrict__ pw,
                                                unsigned short* __restrict__ wq1,
                                                unsigned short* __restrict__ wp) {
  if (blockIdx.x >= 512) {                     // weight-conversion tail blocks
    int idx = (blockIdx.x - 512) * 256 + threadIdx.x;   // 0..32767
    wq1[idx] = f2b(qw[49152 + idx]);
    wq1[idx + 16384] = f2b(qw[49152 + idx + 16384]);
    if (idx < 16384) wq1[idx + 32768] = f2b(qw[49152 + idx + 32768]);
    wp[idx] = f2b(pw[idx]);
    return;
  }

  __shared__ __align__(16) unsigned short As[16 * 136];
  int m0 = blockIdx.x * 16;
  int tid = threadIdx.x;
  int b = m0 >> 12, i = (m0 >> 6) & 63, j0 = m0 & 63;

  for (int idx = tid; idx < 2048; idx += 256) {
    int c = idx >> 4, jl = idx & 15;
    As[jl * 136 + c] =
        f2b(x[(size_t)b * 524288 + (size_t)c * 4096 + i * 64 + j0 + jl]);
  }
  __syncthreads();

  int w = tid >> 6, lane = tid & 63;
  int quad = lane >> 4, l16 = lane & 15;
  short8 a[4];
#pragma unroll
  for (int kc = 0; kc < 4; ++kc)
    a[kc] = *(const short8*)(As + l16 * 136 + kc * 32 + quad * 8);
#pragma unroll
  for (int nt = 0; nt < 6; ++nt) {
    int col = w * 96 + nt * 16 + l16;
    const float* wrow = qw + (size_t)col * 128 + quad * 8;
    f32x4 c = {0.f, 0.f, 0.f, 0.f};
#pragma unroll
    for (int kc = 0; kc < 4; ++kc)
      c = __builtin_amdgcn_mfma_f32_16x16x32_bf16(a[kc], ldw8(wrow + kc * 32), c, 0, 0, 0);
    float bv = qb[col];
#pragma unroll
    for (int r2 = 0; r2 < 4; ++r2)
      qkv[(size_t)(m0 + quad * 4 + r2) * 384 + col] = f2b(c[r2] + bv);
  }
}

// ---------- MFMA GEMM (qkv1): C[M,N] = A[M,128] * W[N,128]^T + bias -------
__global__ __launch_bounds__(256) void gemm_mfma(const unsigned short* __restrict__ A,
                                                 const unsigned short* __restrict__ W,
                                                 const float* __restrict__ bias,
                                                 unsigned short* __restrict__ Cmat,
                                                 int N) {
  int m0 = blockIdx.x * 64, n0 = blockIdx.y * 64;
  int tid = threadIdx.x;
  int w = tid >> 6, lane = tid & 63;
  int quad = lane >> 4, l16 = lane & 15;

  const short8* ap =
      (const short8*)(A + (size_t)(m0 + w * 16 + l16) * 128 + quad * 8);
  short8 a[4];
#pragma unroll
  for (int kc = 0; kc < 4; ++kc) a[kc] = ap[kc * 4];

  f32x4 acc[4];
#pragma unroll
  for (int nt = 0; nt < 4; ++nt) {
    const short8* bp =
        (const short8*)(W + (size_t)(n0 + nt * 16 + l16) * 128 + quad * 8);
    f32x4 c = {0.f, 0.f, 0.f, 0.f};
#pragma unroll
    for (int kc = 0; kc < 4; ++kc)
      c = __builtin_amdgcn_mfma_f32_16x16x32_bf16(a[kc], bp[kc * 4], c, 0, 0, 0);
    acc[nt] = c;
  }

#pragma unroll
  for (int nt = 0; nt < 4; ++nt) {
    int col = n0 + nt * 16 + l16;
    float bv = bias[col];
#pragma unroll
    for (int r = 0; r < 4; ++r) {
      int m = m0 + w * 16 + quad * 4 + r;
      Cmat[(size_t)m * N + col] = f2b(acc[nt][r] + bv);
    }
  }
}

// ---------- fused neighborhood attention (4 heads) + proj ----------
// Block: 8x4 px tile, ALL 4 heads, 512 threads. Thread = (px, head, quarter).
// Phase 1: stage K/V halo (140 rows x 128ch) in LDS. Phase 2: 49-tap QK dots
// + softmax + PV exactly as v6 (per-head). Phase 3: pack out rows (32x128
// bf16) into LDS (reusing kbuf), proj via MFMA with bf16 W, write y.
#define RSTRIDE 136
__global__ __launch_bounds__(512, 1) void attnproj(const unsigned short* __restrict__ qkvp,
                                                   const float* __restrict__ rpb,
                                                   const unsigned short* __restrict__ wp,
                                                   const float* __restrict__ pbias,
                                                   unsigned short* __restrict__ y) {
  __shared__ __align__(16) unsigned short kbuf[140 * RSTRIDE];
  __shared__ __align__(16) unsigned short vbuf[140 * RSTRIDE];
  __shared__ float rb[676];
  __shared__ float sc[128][52];

  int ti = blockIdx.x >> 4, tj = blockIdx.x & 15;   // 8 x 16 tiles of 8x4 px
  int bz = blockIdx.y;
  int tid = threadIdx.x;
  int bi0 = ti * 8 - 3, bj0 = tj * 4 - 3;           // halo origin

  for (int t = tid; t < 676; t += 512) rb[t] = rpb[t];

  for (int t = tid; t < 4480; t += 512) {
    int row = t >> 5;            // 0..139
    int sub = t & 31;
    int isv = sub >> 4;          // 0=K, 1=V
    int c = sub & 15;            // 16 uint4 per 128-ch row
    int ri = row / 10, rj = row - ri * 10;
    int gi = bi0 + ri, gj = bj0 + rj;
    uint4 val = make_uint4(0, 0, 0, 0);
    if ((unsigned)gi < 64u && (unsigned)gj < 64u) {
      int pixn = (bz * 64 + gi) * 64 + gj;
      val = *(const uint4*)(qkvp + (size_t)pixn * 384 + 128 + isv * 128 + c * 8);
    }
    *(uint4*)((isv ? vbuf : kbuf) + row * RSTRIDE + c * 8) = val;
  }
  __syncthreads();

  int r = tid & 3;
  int hh = (tid >> 2) & 3;       // head 0..3
  int px = tid >> 4;             // 0..31
  int ph = px * 4 + hh;
  int pi = px >> 2, pj = px & 3;
  int i = ti * 8 + pi, j = tj * 4 + pj;
  int si = min(max(i - 3, 0), 57), sj = min(max(j - 3, 0), 57);
  int li = si - bi0, lj = sj - bj0;
  int oi = i - si, oj = j - sj;
  int pix = (bz * 64 + i) * 64 + j;

  const float scale = 0.17677669529663687f;   // 32^-0.5
  float q[8];
  {
    uint4 t = *(const uint4*)(qkvp + (size_t)pix * 384 + hh * 32 + r * 8);
    q[0] = bflo(t.x) * scale;  q[1] = bfhi(t.x) * scale;
    q[2] = bflo(t.y) * scale;  q[3] = bfhi(t.y) * scale;
    q[4] = bflo(t.z) * scale;  q[5] = bfhi(t.z) * scale;
    q[6] = bflo(t.w) * scale;  q[7] = bfhi(t.w) * scale;
  }

  const unsigned short* kh = kbuf + hh * 32 + r * 8;
  const unsigned short* vh = vbuf + hh * 32 + r * 8;
  const float* rbh = rb + hh * 169;

#pragma unroll
  for (int p = 0; p < 7; ++p) {
#pragma unroll
    for (int qq = 0; qq < 7; ++qq) {
      int n = (li + p) * 10 + (lj + qq);
      uint4 t = *(const uint4*)(kh + n * RSTRIDE);
      float dot = q[0] * bflo(t.x) + q[1] * bfhi(t.x)
                + q[2] * bflo(t.y) + q[3] * bfhi(t.y)
                + q[4] * bflo(t.z) + q[5] * bfhi(t.z)
                + q[6] * bflo(t.w) + q[7] * bfhi(t.w);
      dot += __shfl_xor(dot, 1);
      dot += __shfl_xor(dot, 2);
      if (r == 0) sc[ph][p * 7 + qq] = dot + rbh[(p + 6 - oi) * 13 + (qq + 6 - oj)];
    }
  }
  __syncthreads();

  float m = -INFINITY;
#pragma unroll
  for (int n = 0; n < 49; ++n) m = fmaxf(m, sc[ph][n]);

  float sum = 0.f;
  float acc[8] = {0.f, 0.f, 0.f, 0.f, 0.f, 0.f, 0.f, 0.f};
#pragma unroll
  for (int p = 0; p < 7; ++p) {
#pragma unroll
    for (int qq = 0; qq < 7; ++qq) {
      float e = __expf(sc[ph][p * 7 + qq] - m);
      sum += e;
      int n = (li + p) * 10 + (lj + qq);
      uint4 t = *(const uint4*)(vh + n * RSTRIDE);
      acc[0] += e * bflo(t.x);  acc[1] += e * bfhi(t.x);
      acc[2] += e * bflo(t.y);  acc[3] += e * bfhi(t.y);
      acc[4] += e * bflo(t.z);  acc[5] += e * bfhi(t.z);
      acc[6] += e * bflo(t.w);  acc[7] += e * bfhi(t.w);
    }
  }
  float inv = 1.f / sum;
  uint4 t;
  t.x = pack2(acc[0] * inv, acc[1] * inv);
  t.y = pack2(acc[2] * inv, acc[3] * inv);
  t.z = pack2(acc[4] * inv, acc[5] * inv);
  t.w = pack2(acc[6] * inv, acc[7] * inv);
  // pack attention output rows (32 px x 128 ch bf16) into LDS, reusing kbuf
  // (kbuf's last read is the QK loop, which is before the sync above).
  unsigned short* obuf = kbuf;
  *(uint4*)(obuf + px * RSTRIDE + hh * 32 + r * 8) = t;
  __syncthreads();

  // ---- proj: out32[32,128] @ W[128,128]^T + bias -> y ----
  int w = tid >> 6, lane = tid & 63;
  int quad = lane >> 4, l16 = lane & 15;
  int mt = w & 1;                 // M-tile (2 x 16 rows)
  int ng = w >> 1;                // N-group (4 x 32 cols)
  short8 a[4];
#pragma unroll
  for (int kc = 0; kc < 4; ++kc)
    a[kc] = *(const short8*)(obuf + (mt * 16 + l16) * RSTRIDE + kc * 32 + quad * 8);
#pragma unroll
  for (int s = 0; s < 2; ++s) {
    int col = (ng * 2 + s) * 16 + l16;
    const short8* bp = (const short8*)(wp + (size_t)col * 128 + quad * 8);
    f32x4 c = {0.f, 0.f, 0.f, 0.f};
#pragma unroll
    for (int kc = 0; kc < 4; ++kc)
      c = __builtin_amdgcn_mfma_f32_16x16x32_bf16(a[kc], bp[kc * 4], c, 0, 0, 0);
    float bv = pbias[col];
#pragma unroll
    for (int r2 = 0; r2 < 4; ++r2) {
      int mloc = mt * 16 + quad * 4 + r2;                 // 0..31
      int gpix = (bz * 64 + ti * 8 + (mloc >> 2)) * 64 + tj * 4 + (mloc & 3);
      y[(size_t)gpix * 128 + col] = f2b(c[r2] + bv);
    }
  }
}

// ---------- LayerNorm over C + transpose to (B,C,H,W), fp32 store ----------
// Single-pass vectorized load+reduce (uint4 = 8 bf16 per load).
__global__ __launch_bounds__(256) void ln_out(const unsigned short* __restrict__ y,
                                              const float* __restrict__ g,
                                              const float* __restrict__ bta,
                                              float* __restrict__ out) {
  __shared__ float tile[64][129];
  __shared__ float mean_s[64], rstd_s[64];
  int blk = blockIdx.x;
  int b = blk >> 6, i = blk & 63;
  int tid = threadIdx.x;
  const unsigned short* yrow = y + (size_t)blk * 64 * 128;
  int jj = tid >> 2, qtr = tid & 3;
  float sum = 0.f, sumsq = 0.f;
#pragma unroll
  for (int u = 0; u < 4; ++u) {
    int c = qtr * 32 + u * 8;
    uint4 t = *(const uint4*)(yrow + jj * 128 + c);
    float v0 = bflo(t.x), v1 = bfhi(t.x), v2 = bflo(t.y), v3 = bfhi(t.y);
    float v4 = bflo(t.z), v5 = bfhi(t.z), v6 = bflo(t.w), v7 = bfhi(t.w);
    sum += v0 + v1 + v2 + v3 + v4 + v5 + v6 + v7;
    sumsq += v0*v0 + v1*v1 + v2*v2 + v3*v3 + v4*v4 + v5*v5 + v6*v6 + v7*v7;
    tile[jj][c+0] = v0; tile[jj][c+1] = v1; tile[jj][c+2] = v2; tile[jj][c+3] = v3;
    tile[jj][c+4] = v4; tile[jj][c+5] = v5; tile[jj][c+6] = v6; tile[jj][c+7] = v7;
  }
  sum += __shfl_xor(sum, 1);  sum += __shfl_xor(sum, 2);
  sumsq += __shfl_xor(sumsq, 1);  sumsq += __shfl_xor(sumsq, 2);
  if (qtr == 0) {
    float mu = sum * (1.f / 128.f);
    mean_s[jj] = mu;
    rstd_s[jj] = rsqrtf(sumsq * (1.f / 128.f) - mu * mu + 1e-5f);
  }
  __syncthreads();
  int c0 = tid >> 6;
  int j = tid & 63;
  for (int c = c0; c < 128; c += 4) {
    float v = (tile[j][c] - mean_s[j]) * rstd_s[j] * g[c] + bta[c];
    out[(((size_t)b * 128 + c) * 64 + i) * 64 + j] = v;
  }
}

extern "C" void kernel_launch(void* const* d_in, const int* in_sizes, int n_in,
                              void* d_out, int out_size, void* d_ws, size_t ws_size,
                              hipStream_t stream) {
  (void)in_sizes; (void)n_in; (void)out_size; (void)ws_size;
  const float* x   = (const float*)d_in[0];
  const float* qw  = (const float*)d_in[1];   // (2,384,128)
  const float* qb  = (const float*)d_in[2];   // (2,384)
  const float* rpb = (const float*)d_in[3];   // (2,4,13,13)
  const float* pw  = (const float*)d_in[4];   // (2,128,128)
  const float* pb  = (const float*)d_in[5];   // (2,128)
  const float* lg  = (const float*)d_in[6];
  const float* lb  = (const float*)d_in[7];

  unsigned short* y    = (unsigned short*)d_ws;          // layer outputs (2 MB)
  unsigned short* qkv  = y + (size_t)PIX * 128;          // PIX*384 (6 MB)
  unsigned short* wq1  = qkv + (size_t)PIX * 384;        // 49152 (L1 qkv w)
  unsigned short* wp   = wq1 + 49152;                    // 32768 (proj w, both)
  float* out = (float*)d_out;

  xqkv_cvt<<<640, 256, 0, stream>>>(x, qw, qb, qkv, pw, wq1, wp);            // qkv0+cvt
  attnproj<<<dim3(128, 2), 512, 0, stream>>>(qkv, rpb, wp, pb, y);           // attn0+proj0
  gemm_mfma<<<dim3(128, 6), 256, 0, stream>>>(y, wq1, qb + 384, qkv, 384);   // qkv1
  attnproj<<<dim3(128, 2), 512, 0, stream>>>(qkv, rpb + 676, wp + 16384, pb + 128, y); // attn1+proj1
  ln_out<<<128, 256, 0, stream>>>(y, lg, lb, out);                           // LN
}

// Round 4
// 130.411 us; speedup vs baseline: 1.2147x; 1.0663x over previous
//
#include <hip/hip_runtime.h>
#include <hip/hip_bf16.h>
#include <math.h>

// B=2, C=128, H=W=64, heads=4, head_dim=32, kernel=7 (49 taps), depth=2.
// Inputs fp32, OUTPUT fp32. Intermediates bf16. MFMA GEMMs.
// R22: extend R21's epilogue fusion (validated: 147.8 -> 139.1).
//  - attnproj<0>: attn + proj0 + qkv1 GEMM in-epilogue. y (proj0 out) never
//    touches global memory; writes layer-1 qkv to a SECOND buffer (qkvB --
//    same-buffer write would race other blocks' halo reads of qkvA).
//  - attnproj<1>: attn + proj1 + LayerNorm + NCHW fp32 store in-epilogue.
//    LN input values identical to R21 (bf16-rounded proj rows in LDS);
//    reduction order differs (ulp-level only). 16B stores (block is 4-wide
//    in j); 256 co-resident blocks -> L2 merges lines.
// Chain (3): xqkv_cvt | attnproj<0> | attnproj<1>.
#define PIX 8192
typedef __hip_bfloat16 bf16;
typedef __attribute__((ext_vector_type(8))) short short8;
typedef __attribute__((ext_vector_type(4))) float f32x4;

__device__ inline float bflo(unsigned u) { return __uint_as_float(u << 16); }
__device__ inline float bfhi(unsigned u) { return __uint_as_float(u & 0xffff0000u); }
__device__ inline unsigned short f2b(float f) {
  __hip_bfloat16 h = __float2bfloat16(f);
  return *reinterpret_cast<unsigned short*>(&h);
}
__device__ inline unsigned pack2(float a, float b) {
  return (unsigned)f2b(a) | ((unsigned)f2b(b) << 16);
}
// load 8 consecutive fp32 weights, convert to a bf16 MFMA fragment (xqkv only)
__device__ inline short8 ldw8(const float* __restrict__ p) {
  f32x4 lo = *(const f32x4*)p;
  f32x4 hi = *(const f32x4*)(p + 4);
  short8 r;
  r[0] = (short)f2b(lo[0]); r[1] = (short)f2b(lo[1]);
  r[2] = (short)f2b(lo[2]); r[3] = (short)f2b(lo[3]);
  r[4] = (short)f2b(hi[0]); r[5] = (short)f2b(hi[1]);
  r[6] = (short)f2b(hi[2]); r[7] = (short)f2b(hi[3]);
  return r;
}

// ---------- kernel 1: fused transpose+qkv0 (blocks 0..511) + weight cvt ----
__global__ __launch_bounds__(256) void xqkv_cvt(const float* __restrict__ x,
                                                const float* __restrict__ qw,
                                                const float* __restrict__ qb,
                                                unsigned short* __restrict__ qkv,
                                                const float* __restrict__ pw,
                                                unsigned short* __restrict__ wq1,
                                                unsigned short* __restrict__ wp) {
  if (blockIdx.x >= 512) {                     // weight-conversion tail blocks
    int idx = (blockIdx.x - 512) * 256 + threadIdx.x;   // 0..32767
    wq1[idx] = f2b(qw[49152 + idx]);
    wq1[idx + 16384] = f2b(qw[49152 + idx + 16384]);
    if (idx < 16384) wq1[idx + 32768] = f2b(qw[49152 + idx + 32768]);
    wp[idx] = f2b(pw[idx]);
    return;
  }

  __shared__ __align__(16) unsigned short As[16 * 136];
  int m0 = blockIdx.x * 16;
  int tid = threadIdx.x;
  int b = m0 >> 12, i = (m0 >> 6) & 63, j0 = m0 & 63;

  for (int idx = tid; idx < 2048; idx += 256) {
    int c = idx >> 4, jl = idx & 15;
    As[jl * 136 + c] =
        f2b(x[(size_t)b * 524288 + (size_t)c * 4096 + i * 64 + j0 + jl]);
  }
  __syncthreads();

  int w = tid >> 6, lane = tid & 63;
  int quad = lane >> 4, l16 = lane & 15;
  short8 a[4];
#pragma unroll
  for (int kc = 0; kc < 4; ++kc)
    a[kc] = *(const short8*)(As + l16 * 136 + kc * 32 + quad * 8);
#pragma unroll
  for (int nt = 0; nt < 6; ++nt) {
    int col = w * 96 + nt * 16 + l16;
    const float* wrow = qw + (size_t)col * 128 + quad * 8;
    f32x4 c = {0.f, 0.f, 0.f, 0.f};
#pragma unroll
    for (int kc = 0; kc < 4; ++kc)
      c = __builtin_amdgcn_mfma_f32_16x16x32_bf16(a[kc], ldw8(wrow + kc * 32), c, 0, 0, 0);
    float bv = qb[col];
#pragma unroll
    for (int r2 = 0; r2 < 4; ++r2)
      qkv[(size_t)(m0 + quad * 4 + r2) * 384 + col] = f2b(c[r2] + bv);
  }
}

// ---------- fused neighborhood attention (4 heads) + proj + epilogue ------
// Block: 8x4 px tile, ALL 4 heads, 512 threads. Thread = (px, head, quarter).
// Phase 1: stage K/V halo (140x128ch) in LDS. Phase 2: 49-tap QK + softmax
// + PV (per-head, 4 lanes each). Phase 3: pack attn-out rows into kbuf,
// proj via MFMA -> bf16 rows in vbuf. Phase 4 (MODE 0): qkv1 GEMM -> qkvo.
// Phase 4 (MODE 1): LayerNorm over C + transposed fp32 NCHW store.
#define RSTRIDE 136
template <int MODE>
__global__ __launch_bounds__(512, 1) void attnproj(const unsigned short* __restrict__ qkvp,
                                                   const float* __restrict__ rpb,
                                                   const unsigned short* __restrict__ wp,
                                                   const float* __restrict__ pbias,
                                                   const unsigned short* __restrict__ wq1,
                                                   const float* __restrict__ qb1,
                                                   unsigned short* __restrict__ qkvo,
                                                   const float* __restrict__ g,
                                                   const float* __restrict__ bta,
                                                   float* __restrict__ out) {
  __shared__ __align__(16) unsigned short kbuf[140 * RSTRIDE];
  __shared__ __align__(16) unsigned short vbuf[140 * RSTRIDE];
  __shared__ float rb[676];
  __shared__ float sc[128][52];

  int ti = blockIdx.x >> 4, tj = blockIdx.x & 15;   // 8 x 16 tiles of 8x4 px
  int bz = blockIdx.y;
  int tid = threadIdx.x;
  int bi0 = ti * 8 - 3, bj0 = tj * 4 - 3;           // halo origin

  for (int t = tid; t < 676; t += 512) rb[t] = rpb[t];

  for (int t = tid; t < 4480; t += 512) {
    int row = t >> 5;            // 0..139
    int sub = t & 31;
    int isv = sub >> 4;          // 0=K, 1=V
    int c = sub & 15;            // 16 uint4 per 128-ch row
    int ri = row / 10, rj = row - ri * 10;
    int gi = bi0 + ri, gj = bj0 + rj;
    uint4 val = make_uint4(0, 0, 0, 0);
    if ((unsigned)gi < 64u && (unsigned)gj < 64u) {
      int pixn = (bz * 64 + gi) * 64 + gj;
      val = *(const uint4*)(qkvp + (size_t)pixn * 384 + 128 + isv * 128 + c * 8);
    }
    *(uint4*)((isv ? vbuf : kbuf) + row * RSTRIDE + c * 8) = val;
  }
  __syncthreads();

  int r = tid & 3;
  int hh = (tid >> 2) & 3;       // head 0..3
  int px = tid >> 4;             // 0..31
  int ph = px * 4 + hh;
  int pi = px >> 2, pj = px & 3;
  int i = ti * 8 + pi, j = tj * 4 + pj;
  int si = min(max(i - 3, 0), 57), sj = min(max(j - 3, 0), 57);
  int li = si - bi0, lj = sj - bj0;
  int oi = i - si, oj = j - sj;
  int pix = (bz * 64 + i) * 64 + j;

  const float scale = 0.17677669529663687f;   // 32^-0.5
  float q[8];
  {
    uint4 t = *(const uint4*)(qkvp + (size_t)pix * 384 + hh * 32 + r * 8);
    q[0] = bflo(t.x) * scale;  q[1] = bfhi(t.x) * scale;
    q[2] = bflo(t.y) * scale;  q[3] = bfhi(t.y) * scale;
    q[4] = bflo(t.z) * scale;  q[5] = bfhi(t.z) * scale;
    q[6] = bflo(t.w) * scale;  q[7] = bfhi(t.w) * scale;
  }

  const unsigned short* kh = kbuf + hh * 32 + r * 8;
  const unsigned short* vh = vbuf + hh * 32 + r * 8;
  const float* rbh = rb + hh * 169;

#pragma unroll
  for (int p = 0; p < 7; ++p) {
#pragma unroll
    for (int qq = 0; qq < 7; ++qq) {
      int n = (li + p) * 10 + (lj + qq);
      uint4 t = *(const uint4*)(kh + n * RSTRIDE);
      float dot = q[0] * bflo(t.x) + q[1] * bfhi(t.x)
                + q[2] * bflo(t.y) + q[3] * bfhi(t.y)
                + q[4] * bflo(t.z) + q[5] * bfhi(t.z)
                + q[6] * bflo(t.w) + q[7] * bfhi(t.w);
      dot += __shfl_xor(dot, 1);
      dot += __shfl_xor(dot, 2);
      if (r == 0) sc[ph][p * 7 + qq] = dot + rbh[(p + 6 - oi) * 13 + (qq + 6 - oj)];
    }
  }
  __syncthreads();

  float m = -INFINITY;
#pragma unroll
  for (int n = 0; n < 49; ++n) m = fmaxf(m, sc[ph][n]);

  float sum = 0.f;
  float acc[8] = {0.f, 0.f, 0.f, 0.f, 0.f, 0.f, 0.f, 0.f};
#pragma unroll
  for (int p = 0; p < 7; ++p) {
#pragma unroll
    for (int qq = 0; qq < 7; ++qq) {
      float e = __expf(sc[ph][p * 7 + qq] - m);
      sum += e;
      int n = (li + p) * 10 + (lj + qq);
      uint4 t = *(const uint4*)(vh + n * RSTRIDE);
      acc[0] += e * bflo(t.x);  acc[1] += e * bfhi(t.x);
      acc[2] += e * bflo(t.y);  acc[3] += e * bfhi(t.y);
      acc[4] += e * bflo(t.z);  acc[5] += e * bfhi(t.z);
      acc[6] += e * bflo(t.w);  acc[7] += e * bfhi(t.w);
    }
  }
  float inv = 1.f / sum;
  uint4 t;
  t.x = pack2(acc[0] * inv, acc[1] * inv);
  t.y = pack2(acc[2] * inv, acc[3] * inv);
  t.z = pack2(acc[4] * inv, acc[5] * inv);
  t.w = pack2(acc[6] * inv, acc[7] * inv);
  // pack attention output rows (32 px x 128 ch bf16) into kbuf (its last
  // read -- the QK loop -- is before the sync above).
  unsigned short* obuf = kbuf;
  *(uint4*)(obuf + px * RSTRIDE + hh * 32 + r * 8) = t;
  __syncthreads();

  // ---- proj: obuf[32,128] @ Wp[128,128]^T + bias -> bf16 rows in vbuf ----
  // (vbuf's last read is the PV loop, before the sync above.)
  unsigned short* ybuf = vbuf;
  int w = tid >> 6, lane = tid & 63;
  int quad = lane >> 4, l16 = lane & 15;
  int mt = w & 1;                 // M-tile (2 x 16 rows)
  int ng = w >> 1;                // N-group (4 x 32 cols)
  {
    short8 a[4];
#pragma unroll
    for (int kc = 0; kc < 4; ++kc)
      a[kc] = *(const short8*)(obuf + (mt * 16 + l16) * RSTRIDE + kc * 32 + quad * 8);
#pragma unroll
    for (int s = 0; s < 2; ++s) {
      int col = (ng * 2 + s) * 16 + l16;
      const short8* bp = (const short8*)(wp + (size_t)col * 128 + quad * 8);
      f32x4 c = {0.f, 0.f, 0.f, 0.f};
#pragma unroll
      for (int kc = 0; kc < 4; ++kc)
        c = __builtin_amdgcn_mfma_f32_16x16x32_bf16(a[kc], bp[kc * 4], c, 0, 0, 0);
      float bv = pbias[col];
#pragma unroll
      for (int r2 = 0; r2 < 4; ++r2)
        ybuf[(mt * 16 + quad * 4 + r2) * RSTRIDE + col] = f2b(c[r2] + bv);
    }
  }
  __syncthreads();

  if constexpr (MODE == 0) {
    // ---- qkv1: ybuf[32,128] @ Wq1[384,128]^T + qb1 -> qkvo (global) ----
    short8 ay[2][4];
#pragma unroll
    for (int mt2 = 0; mt2 < 2; ++mt2)
#pragma unroll
      for (int kc = 0; kc < 4; ++kc)
        ay[mt2][kc] = *(const short8*)(ybuf + (mt2 * 16 + l16) * RSTRIDE + kc * 32 + quad * 8);
#pragma unroll
    for (int s = 0; s < 3; ++s) {
      int col = (w * 3 + s) * 16 + l16;
      const short8* bp = (const short8*)(wq1 + (size_t)col * 128 + quad * 8);
      float bv = qb1[col];
#pragma unroll
      for (int mt2 = 0; mt2 < 2; ++mt2) {
        f32x4 c = {0.f, 0.f, 0.f, 0.f};
#pragma unroll
        for (int kc = 0; kc < 4; ++kc)
          c = __builtin_amdgcn_mfma_f32_16x16x32_bf16(ay[mt2][kc], bp[kc * 4], c, 0, 0, 0);
#pragma unroll
        for (int r2 = 0; r2 < 4; ++r2) {
          int mloc = mt2 * 16 + quad * 4 + r2;             // 0..31
          int gpix = (bz * 64 + ti * 8 + (mloc >> 2)) * 64 + tj * 4 + (mloc & 3);
          qkvo[(size_t)gpix * 384 + col] = f2b(c[r2] + bv);
        }
      }
    }
  } else {
    // ---- LayerNorm over C + transpose to (B,C,H,W) fp32 ----
    int px2 = tid >> 4, sub = tid & 15;     // 16 lanes per pixel
    uint4 tv = *(const uint4*)(ybuf + px2 * RSTRIDE + sub * 8);
    float v[8];
    v[0] = bflo(tv.x); v[1] = bfhi(tv.x); v[2] = bflo(tv.y); v[3] = bfhi(tv.y);
    v[4] = bflo(tv.z); v[5] = bfhi(tv.z); v[6] = bflo(tv.w); v[7] = bfhi(tv.w);
    float sum2 = 0.f, sumsq = 0.f;
#pragma unroll
    for (int k = 0; k < 8; ++k) { sum2 += v[k]; sumsq += v[k] * v[k]; }
    sum2 += __shfl_xor(sum2, 1);  sumsq += __shfl_xor(sumsq, 1);
    sum2 += __shfl_xor(sum2, 2);  sumsq += __shfl_xor(sumsq, 2);
    sum2 += __shfl_xor(sum2, 4);  sumsq += __shfl_xor(sumsq, 4);
    sum2 += __shfl_xor(sum2, 8);  sumsq += __shfl_xor(sumsq, 8);
    float mu = sum2 * (1.f / 128.f);
    float rstd = rsqrtf(sumsq * (1.f / 128.f) - mu * mu + 1e-5f);
    int i2 = ti * 8 + (px2 >> 2), j2 = tj * 4 + (px2 & 3);
    int c0 = sub * 8;
    f32x4 g0 = *(const f32x4*)(g + c0),   g1 = *(const f32x4*)(g + c0 + 4);
    f32x4 b0 = *(const f32x4*)(bta + c0), b1 = *(const f32x4*)(bta + c0 + 4);
#pragma unroll
    for (int k = 0; k < 8; ++k) {
      float gg = (k < 4) ? g0[k] : g1[k - 4];
      float bb = (k < 4) ? b0[k] : b1[k - 4];
      float o = (v[k] - mu) * rstd * gg + bb;
      out[(((size_t)bz * 128 + c0 + k) * 64 + i2) * 64 + j2] = o;
    }
  }
}

extern "C" void kernel_launch(void* const* d_in, const int* in_sizes, int n_in,
                              void* d_out, int out_size, void* d_ws, size_t ws_size,
                              hipStream_t stream) {
  (void)in_sizes; (void)n_in; (void)out_size; (void)ws_size;
  const float* x   = (const float*)d_in[0];
  const float* qw  = (const float*)d_in[1];   // (2,384,128)
  const float* qb  = (const float*)d_in[2];   // (2,384)
  const float* rpb = (const float*)d_in[3];   // (2,4,13,13)
  const float* pw  = (const float*)d_in[4];   // (2,128,128)
  const float* pb  = (const float*)d_in[5];   // (2,128)
  const float* lg  = (const float*)d_in[6];
  const float* lb  = (const float*)d_in[7];

  unsigned short* qkvA = (unsigned short*)d_ws;          // PIX*384 (6 MB)
  unsigned short* qkvB = qkvA + (size_t)PIX * 384;       // PIX*384 (6 MB)
  unsigned short* wq1  = qkvB + (size_t)PIX * 384;       // 49152 (L1 qkv w)
  unsigned short* wp   = wq1 + 49152;                    // 32768 (proj w, both)
  float* out = (float*)d_out;

  xqkv_cvt<<<640, 256, 0, stream>>>(x, qw, qb, qkvA, pw, wq1, wp);
  attnproj<0><<<dim3(128, 2), 512, 0, stream>>>(qkvA, rpb, wp, pb, wq1,
                                                qb + 384, qkvB, nullptr,
                                                nullptr, nullptr);
  attnproj<1><<<dim3(128, 2), 512, 0, stream>>>(qkvB, rpb + 676, wp + 16384,
                                                pb + 128, nullptr, nullptr,
                                                nullptr, lg, lb, out);
}